// Round 14
// baseline (475.873 us; speedup 1.0000x reference)
//
#include <hip/hip_runtime.h>
#include <math.h>

#define T_LEN 1024
#define BATCH 1024
#define H 64
#define NB 4   // batches per block; 4x M-replication in the 16-row A tile

typedef __attribute__((ext_vector_type(4))) int   i32x4;

// ---- fast device math (v_exp_f32 / v_rcp_f32) ----
__device__ __forceinline__ float fast_rcp(float x) { return __builtin_amdgcn_rcpf(x); }
__device__ __forceinline__ float fast_sigmoid(float x) {
  return fast_rcp(1.0f + __expf(-x));
}
// sigmoid with pre-negated argument: sigmoid(x) where nx = -x is given
__device__ __forceinline__ float fast_sigmoid_n(float nx) {
  return fast_rcp(1.0f + __expf(nx));
}
// tanh(x) = 1 - 2/(1+exp(2x)) — exact identity; saturates correctly.
__device__ __forceinline__ float fast_tanh(float x) {
  return fmaf(-2.0f, fast_rcp(1.0f + __expf(2.0f * x)), 1.0f);
}

// ===================== encoder =====================
// (validated R12, ~348us, absmax 4.9e-4): grid 256 x 256thr, 1 block/CU,
// NB=4 batches, 4x M-replication -> lane (q,l15) holds the complete i,f,g,o
// quadruple for its ONE cell (batch q, unit 16wv+l15). Gates GEMM in i8
// double-digit fixed point:
//   h=(a*128+b)*2^-13, W=(wa*128+wb)*2^-15
//   h.W = ((a.wa<<7) + a.wb + b.wa) * 2^-21   (b.wb dropped: ~1.5e-5/term)
// 3x mfma_i32_16x16x64_i8 per gate — R13's Karatsuba 2-MFMA variant FAILED:
// S=127*P1+Px puts b.wb at 127x its true weight (absmax 2.4e-3). Two
// products cannot recover three weighted terms; 3 MFMAs is the floor here.
// h digits exchange through LDS byte arrays, parity dbuf, one lgkm-only
// barrier/step.
__global__ __launch_bounds__(256, 1) void encoder_kernel(
    const float* __restrict__ x,      // [T, BATCH]
    const float* __restrict__ Wih_e,  // [256, 1]
    const float* __restrict__ Whh_e,  // [256, 64]
    const float* __restrict__ bih_e,  // [256]
    const float* __restrict__ bhh_e,  // [256]
    float* __restrict__ h_enc)        // [BATCH, 64]
{
  // [parity][digit][bat*H + u]
  __shared__ __align__(16) signed char dig[2][2][NB * H];   // 2 KB
  __shared__ float x_lds[T_LEN * NB];                       // 16 KB

  const int tid  = threadIdx.x;
  const int lane = tid & 63;
  const int wv   = tid >> 6;        // n-tile group (0..3)
  const int q    = lane >> 4;
  const int l15  = lane & 15;
  const int b0   = blockIdx.x * NB;
  const int u    = wv * 16 + l15;   // this lane's hidden unit
  const int mb   = l15 >> 2;        // A-row batch (4x replication)
  const int bat  = q;               // this lane's cell batch (non-redundant)

  // ---- persistent weight digit fragments: 4 gates x {wa,wb}, 32 VGPRs ----
  i32x4 Ba[4], Bb[4];
  float wih_g[4], bias_g[4];
  for (int g = 0; g < 4; ++g) {
    const int n = g * 64 + u;       // gate row
    const float* wp = &Whh_e[n * H + q * 16];
    union { i32x4 v; signed char c[16]; } ua, ub;
#pragma unroll
    for (int j = 0; j < 16; ++j) {
      const int wint = (int)rintf(wp[j] * 32768.f);   // |.| <= 4096
      const int wa = (wint + 64) >> 7;                // [-32, 32]
      const int wb = wint - (wa << 7);                // [-64, 63]
      ua.c[j] = (signed char)wa;
      ub.c[j] = (signed char)wb;
    }
    Ba[g] = ua.v; Bb[g] = ub.v;
    wih_g[g]  = Wih_e[n];
    bias_g[g] = bih_e[n] + bhh_e[n];
  }

  // ---- one-time staging: x (float4 rows, layout [t][b]) + zero digits ----
  for (int t = tid; t < T_LEN; t += 256)
    *(float4*)&x_lds[t * NB] = *(const float4*)&x[t * BATCH + b0];
  for (int i = tid; i < 2 * NB * H; i += 256)
    ((signed char*)dig[0])[i] = 0;      // h=0 -> both digits 0
  __syncthreads();

  float c = 0.0f, h_last = 0.0f;
  const i32x4 izero = {0, 0, 0, 0};

#define ENC_STEP(P, TT)                                                        \
  {                                                                            \
    const i32x4 Aa = *(const i32x4*)&dig[P][0][mb * H + q * 16];               \
    const i32x4 Ab = *(const i32x4*)&dig[P][1][mb * H + q * 16];               \
    const float xv = x_lds[(TT) * NB + bat];                                   \
    float G[4];                                                                \
    _Pragma("unroll")                                                          \
    for (int g = 0; g < 4; ++g) {                                              \
      i32x4 P1 = __builtin_amdgcn_mfma_i32_16x16x64_i8(Aa, Ba[g], izero, 0, 0, 0); \
      i32x4 Pc = __builtin_amdgcn_mfma_i32_16x16x64_i8(Ab, Ba[g], izero, 0, 0, 0); \
      Pc = __builtin_amdgcn_mfma_i32_16x16x64_i8(Aa, Bb[g], Pc, 0, 0, 0);      \
      const int S = (P1[0] << 7) + Pc[0];      /* exact, < 2^25 */             \
      G[g] = fmaf((float)S, 0x1.0p-21f, fmaf(xv, wih_g[g], bias_g[g]));        \
    }                                                                          \
    const float iv = fast_sigmoid(G[0]);                                       \
    const float fv = fast_sigmoid(G[1]);                                       \
    const float gv = fast_tanh(G[2]);                                          \
    const float ov = fast_sigmoid(G[3]);                                       \
    c = fmaf(fv, c, iv * gv);                                                  \
    h_last = ov * fast_tanh(c);                                                \
    const int v  = (int)rintf(h_last * 8192.f);  /* [-8192, 8192] */           \
    const int ad = (v + 64) >> 7;                /* [-64, 64] */               \
    const int bd = v - (ad << 7);                /* [-64, 63] */               \
    dig[1 - (P)][0][bat * H + u] = (signed char)ad;                            \
    dig[1 - (P)][1][bat * H + u] = (signed char)bd;                            \
    __syncthreads();                                                           \
  }

  for (int t = 0; t < T_LEN; t += 2) {
    ENC_STEP(0, t)
    ENC_STEP(1, t + 1)
  }
#undef ENC_STEP

  h_enc[(b0 + bat) * H + u] = h_last;
}

// ===================== decoder =====================
// Wide form: one lane per batch, 16 waves, grid 16. The recurrence is a
// FIXED scalar map (h,c)->F(h,c) per batch (constant gate bases). R14:
// exact-periodicity early exit — if the fp32 state before an 8-step group
// equals the state after it BIT-FOR-BIT, the whole future sequence repeats
// that group's 8 outputs (deterministic identical code each group), so we
// fill the rest from the buffered group. Exact for ANY inputs; worst case
// (never periodic) adds ~6 ops per 8 steps.
__global__ __launch_bounds__(64) void decoder_kernel(
    const float* __restrict__ h_enc,  // [BATCH, 64]
    const float* __restrict__ Wih,    // [4, 64]
    const float* __restrict__ Whh,    // [4, 1]
    const float* __restrict__ bih,    // [4]
    const float* __restrict__ bhh,    // [4]
    float* __restrict__ out)          // [T, BATCH]
{
  const int b = blockIdx.x * blockDim.x + threadIdx.x;

  float a0 = bih[0] + bhh[0];
  float a1 = bih[1] + bhh[1];
  float a2 = bih[2] + bhh[2];
  float a3 = bih[3] + bhh[3];
#pragma unroll 8
  for (int k = 0; k < H; ++k) {
    const float hv = h_enc[b * H + k];
    a0 = fmaf(Wih[0 * H + k], hv, a0);
    a1 = fmaf(Wih[1 * H + k], hv, a1);
    a2 = fmaf(Wih[2 * H + k], hv, a2);
    a3 = fmaf(Wih[3 * H + k], hv, a3);
  }
  const float w0 = Whh[0], w1 = Whh[1], w2 = Whh[2], w3 = Whh[3];
  const float na0 = -a0, nw0 = -w0;   // i gate, negated
  const float na1 = -a1, nw1 = -w1;   // f gate, negated
  const float na3 = -a3, nw3 = -w3;   // o gate, negated

  float h = 0.0f, c = 0.0f;
  float buf[8];
  float* outp = out + b;
  int t = 0;
  for (; t < T_LEN; ) {
    const float h_prev = h, c_prev = c;
#pragma unroll
    for (int uu = 0; uu < 8; ++uu) {
      const float iv = fast_sigmoid_n(fmaf(nw0, h, na0));
      const float fv = fast_sigmoid_n(fmaf(nw1, h, na1));
      const float gv = fast_tanh(fmaf(w2, h, a2));
      const float ov = fast_sigmoid_n(fmaf(nw3, h, na3));
      c = fmaf(fv, c, iv * gv);
      h = ov * fast_tanh(c);
      buf[uu] = h;
    }
#pragma unroll
    for (int uu = 0; uu < 8; ++uu)
      outp[(t + uu) * BATCH] = buf[uu];
    t += 8;
    // exact 8-periodicity: state repeats bit-for-bit -> future == this group
    if (__all((h == h_prev) && (c == c_prev))) break;
  }
  // store-only fill: repeat the periodic group (exact)
  for (; t < T_LEN; t += 8) {
#pragma unroll
    for (int uu = 0; uu < 8; ++uu)
      outp[(t + uu) * BATCH] = buf[uu];
  }
}

extern "C" void kernel_launch(void* const* d_in, const int* in_sizes, int n_in,
                              void* d_out, int out_size, void* d_ws, size_t ws_size,
                              hipStream_t stream) {
  const float* x     = (const float*)d_in[0];
  const float* Wih_e = (const float*)d_in[1];
  const float* Whh_e = (const float*)d_in[2];
  const float* bih_e = (const float*)d_in[3];
  const float* bhh_e = (const float*)d_in[4];
  const float* Wih_d = (const float*)d_in[5];
  const float* Whh_d = (const float*)d_in[6];
  const float* bih_d = (const float*)d_in[7];
  const float* bhh_d = (const float*)d_in[8];
  float* out = (float*)d_out;

  float* h_enc = (float*)d_ws;  // 1024*64*4 = 256 KB scratch

  encoder_kernel<<<BATCH / NB, 256, 0, stream>>>(x, Wih_e, Whh_e, bih_e, bhh_e, h_enc);
  decoder_kernel<<<BATCH / 64, 64, 0, stream>>>(h_enc, Wih_d, Whh_d, bih_d, bhh_d, out);
}

// Round 15
// 469.248 us; speedup vs baseline: 1.0141x; 1.0141x over previous
//
#include <hip/hip_runtime.h>
#include <math.h>

#define T_LEN 1024
#define BATCH 1024
#define H 64
#define NB 4   // batches per block; 4x M-replication in the 16-row A tile

typedef __attribute__((ext_vector_type(4))) int   i32x4;

// ---- fast device math (v_exp_f32 / v_rcp_f32) ----
__device__ __forceinline__ float fast_rcp(float x) { return __builtin_amdgcn_rcpf(x); }
__device__ __forceinline__ float fast_sigmoid(float x) {
  return fast_rcp(1.0f + __expf(-x));
}
// sigmoid with pre-negated argument: sigmoid(x) where nx = -x is given
__device__ __forceinline__ float fast_sigmoid_n(float nx) {
  return fast_rcp(1.0f + __expf(nx));
}
// tanh(x) = 1 - 2/(1+exp(2x)) — exact identity; saturates correctly.
__device__ __forceinline__ float fast_tanh(float x) {
  return fmaf(-2.0f, fast_rcp(1.0f + __expf(2.0f * x)), 1.0f);
}

// ===================== encoder =====================
// (best measured: 347-348us, absmax 4.9e-4) Grid 256 x 256thr, 1 block/CU,
// NB=4 batches, 4x M-replication -> lane (q,l15) holds the complete i,f,g,o
// quadruple for its ONE cell (batch q, unit 16wv+l15). Gates GEMM in i8
// double-digit fixed point:
//   h=(a*128+b)*2^-13, W=(wa*128+wb)*2^-15
//   h.W = ((a.wa<<7) + a.wb + b.wa) * 2^-21   (b.wb dropped: ~1.5e-5/term)
// 3x mfma_i32_16x16x64_i8 per gate (R13 proved 2-MFMA Karatsuba fails:
// b.wb enters at 127x weight). h digits exchange through LDS byte arrays,
// parity dbuf, one lgkm-only barrier/step.
//
// Floor evidence: 813 cyc/step = MFMA-pipe 200 (48 MFMA/CU, minimum for
// 16-row M-tile at 4 batches/CU; NB=2 layouts measured 2x work — R6/R7) +
// VALU ~340 (10 trans/cell irreducible) + ~270 chain stall at 1 wave/SIMD
// (the only added-occupancy structure, R7, measured 440us — dominated).
__global__ __launch_bounds__(256, 1) void encoder_kernel(
    const float* __restrict__ x,      // [T, BATCH]
    const float* __restrict__ Wih_e,  // [256, 1]
    const float* __restrict__ Whh_e,  // [256, 64]
    const float* __restrict__ bih_e,  // [256]
    const float* __restrict__ bhh_e,  // [256]
    float* __restrict__ h_enc)        // [BATCH, 64]
{
  // [parity][digit][bat*H + u]
  __shared__ __align__(16) signed char dig[2][2][NB * H];   // 2 KB
  __shared__ float x_lds[T_LEN * NB];                       // 16 KB

  const int tid  = threadIdx.x;
  const int lane = tid & 63;
  const int wv   = tid >> 6;        // n-tile group (0..3)
  const int q    = lane >> 4;
  const int l15  = lane & 15;
  const int b0   = blockIdx.x * NB;
  const int u    = wv * 16 + l15;   // this lane's hidden unit
  const int mb   = l15 >> 2;        // A-row batch (4x replication)
  const int bat  = q;               // this lane's cell batch (non-redundant)

  // ---- persistent weight digit fragments: 4 gates x {wa,wb}, 32 VGPRs ----
  i32x4 Ba[4], Bb[4];
  float wih_g[4], bias_g[4];
  for (int g = 0; g < 4; ++g) {
    const int n = g * 64 + u;       // gate row
    const float* wp = &Whh_e[n * H + q * 16];
    union { i32x4 v; signed char c[16]; } ua, ub;
#pragma unroll
    for (int j = 0; j < 16; ++j) {
      const int wint = (int)rintf(wp[j] * 32768.f);   // |.| <= 4096
      const int wa = (wint + 64) >> 7;                // [-32, 32]
      const int wb = wint - (wa << 7);                // [-64, 63]
      ua.c[j] = (signed char)wa;
      ub.c[j] = (signed char)wb;
    }
    Ba[g] = ua.v; Bb[g] = ub.v;
    wih_g[g]  = Wih_e[n];
    bias_g[g] = bih_e[n] + bhh_e[n];
  }

  // ---- one-time staging: x (float4 rows, layout [t][b]) + zero digits ----
  for (int t = tid; t < T_LEN; t += 256)
    *(float4*)&x_lds[t * NB] = *(const float4*)&x[t * BATCH + b0];
  for (int i = tid; i < 2 * NB * H; i += 256)
    ((signed char*)dig[0])[i] = 0;      // h=0 -> both digits 0
  __syncthreads();

  float c = 0.0f, h_last = 0.0f;
  const i32x4 izero = {0, 0, 0, 0};

#define ENC_STEP(P, TT)                                                        \
  {                                                                            \
    const i32x4 Aa = *(const i32x4*)&dig[P][0][mb * H + q * 16];               \
    const i32x4 Ab = *(const i32x4*)&dig[P][1][mb * H + q * 16];               \
    const float xv = x_lds[(TT) * NB + bat];                                   \
    float G[4];                                                                \
    _Pragma("unroll")                                                          \
    for (int g = 0; g < 4; ++g) {                                              \
      i32x4 P1 = __builtin_amdgcn_mfma_i32_16x16x64_i8(Aa, Ba[g], izero, 0, 0, 0); \
      i32x4 Pc = __builtin_amdgcn_mfma_i32_16x16x64_i8(Ab, Ba[g], izero, 0, 0, 0); \
      Pc = __builtin_amdgcn_mfma_i32_16x16x64_i8(Aa, Bb[g], Pc, 0, 0, 0);      \
      const int S = (P1[0] << 7) + Pc[0];      /* exact, < 2^25 */             \
      G[g] = fmaf((float)S, 0x1.0p-21f, fmaf(xv, wih_g[g], bias_g[g]));        \
    }                                                                          \
    const float iv = fast_sigmoid(G[0]);                                       \
    const float fv = fast_sigmoid(G[1]);                                       \
    const float gv = fast_tanh(G[2]);                                          \
    const float ov = fast_sigmoid(G[3]);                                       \
    c = fmaf(fv, c, iv * gv);                                                  \
    h_last = ov * fast_tanh(c);                                                \
    const int v  = (int)rintf(h_last * 8192.f);  /* [-8192, 8192] */           \
    const int ad = (v + 64) >> 7;                /* [-64, 64] */               \
    const int bd = v - (ad << 7);                /* [-64, 63] */               \
    dig[1 - (P)][0][bat * H + u] = (signed char)ad;                            \
    dig[1 - (P)][1][bat * H + u] = (signed char)bd;                            \
    __syncthreads();                                                           \
  }

  for (int t = 0; t < T_LEN; t += 2) {
    ENC_STEP(0, t)
    ENC_STEP(1, t + 1)
  }
#undef ENC_STEP

  h_enc[(b0 + bat) * H + u] = h_last;
}

// ===================== decoder =====================
// Wide form: one lane per batch, 16 waves, grid 16. At its latency floor
// (~280 cyc/step: two dependent exp->rcp pairs on the h->c->h critical path;
// only 1024 independent chains exist -> 16 waves max). Fusion variants
// measured 2.5x worse (R9-R11); periodicity early-exit never triggers (R14).
// 8-deep register store buffer keeps store retirement off the chain.
__global__ __launch_bounds__(64) void decoder_kernel(
    const float* __restrict__ h_enc,  // [BATCH, 64]
    const float* __restrict__ Wih,    // [4, 64]
    const float* __restrict__ Whh,    // [4, 1]
    const float* __restrict__ bih,    // [4]
    const float* __restrict__ bhh,    // [4]
    float* __restrict__ out)          // [T, BATCH]
{
  const int b = blockIdx.x * blockDim.x + threadIdx.x;

  float a0 = bih[0] + bhh[0];
  float a1 = bih[1] + bhh[1];
  float a2 = bih[2] + bhh[2];
  float a3 = bih[3] + bhh[3];
#pragma unroll 8
  for (int k = 0; k < H; ++k) {
    const float hv = h_enc[b * H + k];
    a0 = fmaf(Wih[0 * H + k], hv, a0);
    a1 = fmaf(Wih[1 * H + k], hv, a1);
    a2 = fmaf(Wih[2 * H + k], hv, a2);
    a3 = fmaf(Wih[3 * H + k], hv, a3);
  }
  const float w0 = Whh[0], w1 = Whh[1], w2 = Whh[2], w3 = Whh[3];
  const float na0 = -a0, nw0 = -w0;   // i gate, negated
  const float na1 = -a1, nw1 = -w1;   // f gate, negated
  const float na3 = -a3, nw3 = -w3;   // o gate, negated

  float h = 0.0f, c = 0.0f;
  float* outp = out + b;
  for (int t = 0; t < T_LEN; t += 8) {
    float buf[8];
#pragma unroll
    for (int uu = 0; uu < 8; ++uu) {
      const float iv = fast_sigmoid_n(fmaf(nw0, h, na0));
      const float fv = fast_sigmoid_n(fmaf(nw1, h, na1));
      const float gv = fast_tanh(fmaf(w2, h, a2));
      const float ov = fast_sigmoid_n(fmaf(nw3, h, na3));
      c = fmaf(fv, c, iv * gv);
      h = ov * fast_tanh(c);
      buf[uu] = h;
    }
#pragma unroll
    for (int uu = 0; uu < 8; ++uu)
      outp[(t + uu) * BATCH] = buf[uu];
  }
}

extern "C" void kernel_launch(void* const* d_in, const int* in_sizes, int n_in,
                              void* d_out, int out_size, void* d_ws, size_t ws_size,
                              hipStream_t stream) {
  const float* x     = (const float*)d_in[0];
  const float* Wih_e = (const float*)d_in[1];
  const float* Whh_e = (const float*)d_in[2];
  const float* bih_e = (const float*)d_in[3];
  const float* bhh_e = (const float*)d_in[4];
  const float* Wih_d = (const float*)d_in[5];
  const float* Whh_d = (const float*)d_in[6];
  const float* bih_d = (const float*)d_in[7];
  const float* bhh_d = (const float*)d_in[8];
  float* out = (float*)d_out;

  float* h_enc = (float*)d_ws;  // 1024*64*4 = 256 KB scratch

  encoder_kernel<<<BATCH / NB, 256, 0, stream>>>(x, Wih_e, Whh_e, bih_e, bhh_e, h_enc);
  decoder_kernel<<<BATCH / 64, 64, 0, stream>>>(h_enc, Wih_d, Whh_d, bih_d, bhh_d, out);
}

// Round 16
// 464.742 us; speedup vs baseline: 1.0240x; 1.0097x over previous
//
#include <hip/hip_runtime.h>
#include <math.h>

#define T_LEN 1024
#define BATCH 1024
#define H 64
#define NB 4   // batches per block; 4x M-replication in the 16-row A tile

typedef __attribute__((ext_vector_type(4))) int   i32x4;

// ---- fast device math (v_exp_f32 / v_rcp_f32) ----
__device__ __forceinline__ float fast_rcp(float x) { return __builtin_amdgcn_rcpf(x); }
__device__ __forceinline__ float fast_sigmoid(float x) {
  return fast_rcp(1.0f + __expf(-x));
}
// sigmoid with pre-negated argument: sigmoid(x) where nx = -x is given
__device__ __forceinline__ float fast_sigmoid_n(float nx) {
  return fast_rcp(1.0f + __expf(nx));
}
// tanh(x) = 1 - 2/(1+exp(2x)) — exact identity; saturates correctly.
__device__ __forceinline__ float fast_tanh(float x) {
  return fmaf(-2.0f, fast_rcp(1.0f + __expf(2.0f * x)), 1.0f);
}

// ===================== encoder =====================
// (R12/R15 structure, 347-350us validated) Grid 256 x 256thr, 1 block/CU,
// NB=4 batches, 4x M-replication -> lane (q,l15) holds the complete i,f,g,o
// quadruple for its ONE cell (batch q, unit 16wv+l15). Gates GEMM in i8
// double-digit fixed point:
//   h=(a*128+b)*2^-13, W=(wa*128+wb)*2^-15
//   h.W = ((a.wa<<7) + a.wb + b.wa) * 2^-21   (b.wb dropped: ~1.5e-5/term)
// 3x mfma_i32_16x16x64_i8 per gate (R13 proved 2-MFMA Karatsuba fails).
// h digits exchange through LDS byte arrays, parity dbuf, one lgkm-only
// barrier/step.
//
// R16: reciprocal merging in the cell epilogue — rcp(a)*rcp(b)=rcp(a*b):
//   i*g = sigma(G0)*tanh(G2) = (r-1)*rcp((1+p)(r+1)),  p=e^-G0, r=e^{2G2}
//   h   = sigma(G3)*tanh(c)  = (s-1)*rcp((1+u)(s+1)),  u=e^-G3, s=e^{2c}
// 5 exp + 3 rcp = 8 trans/cell (was 10) on the dominant VALU pipe.
// Overflow-safe: |G| <= ~9 -> products <= e^28 << fp32 max.
__global__ __launch_bounds__(256, 1) void encoder_kernel(
    const float* __restrict__ x,      // [T, BATCH]
    const float* __restrict__ Wih_e,  // [256, 1]
    const float* __restrict__ Whh_e,  // [256, 64]
    const float* __restrict__ bih_e,  // [256]
    const float* __restrict__ bhh_e,  // [256]
    float* __restrict__ h_enc)        // [BATCH, 64]
{
  // [parity][digit][bat*H + u]
  __shared__ __align__(16) signed char dig[2][2][NB * H];   // 2 KB
  __shared__ float x_lds[T_LEN * NB];                       // 16 KB

  const int tid  = threadIdx.x;
  const int lane = tid & 63;
  const int wv   = tid >> 6;        // n-tile group (0..3)
  const int q    = lane >> 4;
  const int l15  = lane & 15;
  const int b0   = blockIdx.x * NB;
  const int u    = wv * 16 + l15;   // this lane's hidden unit
  const int mb   = l15 >> 2;        // A-row batch (4x replication)
  const int bat  = q;               // this lane's cell batch (non-redundant)

  // ---- persistent weight digit fragments: 4 gates x {wa,wb}, 32 VGPRs ----
  i32x4 Ba[4], Bb[4];
  float wih_g[4], bias_g[4];
  for (int g = 0; g < 4; ++g) {
    const int n = g * 64 + u;       // gate row
    const float* wp = &Whh_e[n * H + q * 16];
    union { i32x4 v; signed char c[16]; } ua, ub;
#pragma unroll
    for (int j = 0; j < 16; ++j) {
      const int wint = (int)rintf(wp[j] * 32768.f);   // |.| <= 4096
      const int wa = (wint + 64) >> 7;                // [-32, 32]
      const int wb = wint - (wa << 7);                // [-64, 63]
      ua.c[j] = (signed char)wa;
      ub.c[j] = (signed char)wb;
    }
    Ba[g] = ua.v; Bb[g] = ub.v;
    wih_g[g]  = Wih_e[n];
    bias_g[g] = bih_e[n] + bhh_e[n];
  }

  // ---- one-time staging: x (float4 rows, layout [t][b]) + zero digits ----
  for (int t = tid; t < T_LEN; t += 256)
    *(float4*)&x_lds[t * NB] = *(const float4*)&x[t * BATCH + b0];
  for (int i = tid; i < 2 * NB * H; i += 256)
    ((signed char*)dig[0])[i] = 0;      // h=0 -> both digits 0
  __syncthreads();

  float c = 0.0f, h_last = 0.0f;
  const i32x4 izero = {0, 0, 0, 0};

#define ENC_STEP(P, TT)                                                        \
  {                                                                            \
    const i32x4 Aa = *(const i32x4*)&dig[P][0][mb * H + q * 16];               \
    const i32x4 Ab = *(const i32x4*)&dig[P][1][mb * H + q * 16];               \
    const float xv = x_lds[(TT) * NB + bat];                                   \
    float G[4];                                                                \
    _Pragma("unroll")                                                          \
    for (int g = 0; g < 4; ++g) {                                              \
      i32x4 P1 = __builtin_amdgcn_mfma_i32_16x16x64_i8(Aa, Ba[g], izero, 0, 0, 0); \
      i32x4 Pc = __builtin_amdgcn_mfma_i32_16x16x64_i8(Ab, Ba[g], izero, 0, 0, 0); \
      Pc = __builtin_amdgcn_mfma_i32_16x16x64_i8(Aa, Bb[g], Pc, 0, 0, 0);      \
      const int S = (P1[0] << 7) + Pc[0];      /* exact, < 2^25 */             \
      G[g] = fmaf((float)S, 0x1.0p-21f, fmaf(xv, wih_g[g], bias_g[g]));        \
    }                                                                          \
    /* merged-reciprocal cell update: 5 exp + 3 rcp */                         \
    const float p = __expf(-G[0]);            /* i-gate */                     \
    const float r = __expf(2.0f * G[2]);      /* g-gate tanh */               \
    const float fv = fast_sigmoid(G[1]);      /* exp + rcp */                  \
    const float u_ = __expf(-G[3]);           /* o-gate */                     \
    const float ig = (r - 1.0f) * fast_rcp((1.0f + p) * (r + 1.0f));           \
    c = fmaf(fv, c, ig);                                                       \
    const float s = __expf(2.0f * c);                                          \
    h_last = (s - 1.0f) * fast_rcp((1.0f + u_) * (s + 1.0f));                  \
    const int v  = (int)rintf(h_last * 8192.f);  /* [-8192, 8192] */           \
    const int ad = (v + 64) >> 7;                /* [-64, 64] */               \
    const int bd = v - (ad << 7);                /* [-64, 63] */               \
    dig[1 - (P)][0][bat * H + u] = (signed char)ad;                            \
    dig[1 - (P)][1][bat * H + u] = (signed char)bd;                            \
    __syncthreads();                                                           \
  }

  for (int t = 0; t < T_LEN; t += 2) {
    ENC_STEP(0, t)
    ENC_STEP(1, t + 1)
  }
#undef ENC_STEP

  h_enc[(b0 + bat) * H + u] = h_last;
}

// ===================== decoder =====================
// Wide form (validated): one lane per batch, 16 waves, grid 16. At its
// latency floor (~280 cyc/step: two dependent exp->rcp pairs on the h->c->h
// critical path; only 1024 independent chains -> 16 waves). Fusion measured
// 2.5x worse (R9-R11); periodicity exit never triggers (R14). 8-deep
// register store buffer keeps store retirement off the chain.
__global__ __launch_bounds__(64) void decoder_kernel(
    const float* __restrict__ h_enc,  // [BATCH, 64]
    const float* __restrict__ Wih,    // [4, 64]
    const float* __restrict__ Whh,    // [4, 1]
    const float* __restrict__ bih,    // [4]
    const float* __restrict__ bhh,    // [4]
    float* __restrict__ out)          // [T, BATCH]
{
  const int b = blockIdx.x * blockDim.x + threadIdx.x;

  float a0 = bih[0] + bhh[0];
  float a1 = bih[1] + bhh[1];
  float a2 = bih[2] + bhh[2];
  float a3 = bih[3] + bhh[3];
#pragma unroll 8
  for (int k = 0; k < H; ++k) {
    const float hv = h_enc[b * H + k];
    a0 = fmaf(Wih[0 * H + k], hv, a0);
    a1 = fmaf(Wih[1 * H + k], hv, a1);
    a2 = fmaf(Wih[2 * H + k], hv, a2);
    a3 = fmaf(Wih[3 * H + k], hv, a3);
  }
  const float w0 = Whh[0], w1 = Whh[1], w2 = Whh[2], w3 = Whh[3];
  const float na0 = -a0, nw0 = -w0;   // i gate, negated
  const float na1 = -a1, nw1 = -w1;   // f gate, negated
  const float na3 = -a3, nw3 = -w3;   // o gate, negated

  float h = 0.0f, c = 0.0f;
  float* outp = out + b;
  for (int t = 0; t < T_LEN; t += 8) {
    float buf[8];
#pragma unroll
    for (int uu = 0; uu < 8; ++uu) {
      const float iv = fast_sigmoid_n(fmaf(nw0, h, na0));
      const float fv = fast_sigmoid_n(fmaf(nw1, h, na1));
      const float gv = fast_tanh(fmaf(w2, h, a2));
      const float ov = fast_sigmoid_n(fmaf(nw3, h, na3));
      c = fmaf(fv, c, iv * gv);
      h = ov * fast_tanh(c);
      buf[uu] = h;
    }
#pragma unroll
    for (int uu = 0; uu < 8; ++uu)
      outp[(t + uu) * BATCH] = buf[uu];
  }
}

extern "C" void kernel_launch(void* const* d_in, const int* in_sizes, int n_in,
                              void* d_out, int out_size, void* d_ws, size_t ws_size,
                              hipStream_t stream) {
  const float* x     = (const float*)d_in[0];
  const float* Wih_e = (const float*)d_in[1];
  const float* Whh_e = (const float*)d_in[2];
  const float* bih_e = (const float*)d_in[3];
  const float* bhh_e = (const float*)d_in[4];
  const float* Wih_d = (const float*)d_in[5];
  const float* Whh_d = (const float*)d_in[6];
  const float* bih_d = (const float*)d_in[7];
  const float* bhh_d = (const float*)d_in[8];
  float* out = (float*)d_out;

  float* h_enc = (float*)d_ws;  // 1024*64*4 = 256 KB scratch

  encoder_kernel<<<BATCH / NB, 256, 0, stream>>>(x, Wih_e, Whh_e, bih_e, bhh_e, h_enc);
  decoder_kernel<<<BATCH / 64, 64, 0, stream>>>(h_enc, Wih_d, Whh_d, bih_d, bhh_d, out);
}